// Round 13
// baseline (180.583 us; speedup 1.0000x reference)
//
#include <hip/hip_runtime.h>

#define S_SHIFT 9
#define S_NODES 512          // nodes per bucket (dst_local = dst & 511)
#define CAP     10240        // bucket capacity (mean ~8163, +25% slack)
#define CHUNK   4096         // edges per prep block
#define EPTS    16           // edges per scatter thread (CHUNK / 256)
#define NREP    4            // LDS accumulator replicas in agg kernels

// One uniform kernel: fold (all waves) -> {waves 0-3: scatter own chunk |
// waves 4-7: dots}, overlapped via shared barriers (phases are latency-bound,
// so concurrent roles give max() instead of sum()).
// Packed edge: (src << 9) | (dst & 511)   (src < 2^17 -> 26 bits)
__global__ __launch_bounds__(512) void prep_kernel(
    const float* __restrict__ x,
    const int* __restrict__ src, const int* __restrict__ dst,
    int E, int N, int B,
    int* __restrict__ cursor, unsigned* __restrict__ bucket,
    const float* __restrict__ Wl1, const float* __restrict__ Wr1, const float* __restrict__ b1,
    const float* __restrict__ Wl2, const float* __restrict__ Wr2, const float* __restrict__ b2,
    const float* __restrict__ Wfc1, const float* __restrict__ bfc1,
    const float* __restrict__ Wfc2, const float* __restrict__ bfc2,
    float* __restrict__ ga, float2* __restrict__ gbc, float* __restrict__ c01)
{
    __shared__ int hist[256], lbase[256], lcur[256];
    __shared__ float wv[192], uu[128], vl2[128], vr2[128], w2[32];
    int t = threadIdx.x;
    int l = t & 63;          // lane
    int w = t >> 6;          // wave (0..7)

    // ---------------- fold (all waves; redundant per block, coalesced) ----------------
    if (t < 32) w2[t] = Wfc2[t];
    __syncthreads();
    for (int j = 0; j < 16; ++j) {   // uu = Wfc1 @ Wfc2  (Wfc1 [128,32] row-major)
        int i = w + 8 * j;
        float p = (l < 32) ? Wfc1[i * 32 + l] * w2[l] : 0.f;
        for (int m = 16; m; m >>= 1) p += __shfl_xor(p, m);
        if (l == 0) uu[i] = p;
    }
    __syncthreads();
    for (int j = 0; j < 16; ++j) {   // vl2 = Wl2 @ uu, vr2 = Wr2 @ uu ([128,128] row-major)
        int i = w + 8 * j;
        float ua = uu[l], ub = uu[64 + l];
        float pa = Wl2[i * 128 + l] * ua + Wl2[i * 128 + 64 + l] * ub;
        float pb = Wr2[i * 128 + l] * ua + Wr2[i * 128 + 64 + l] * ub;
        for (int m = 32; m; m >>= 1) { pa += __shfl_xor(pa, m); pb += __shfl_xor(pb, m); }
        if (l == 0) { vl2[i] = pa; vr2[i] = pb; }
    }
    __syncthreads();
    for (int j = 0; j < 8; ++j) {    // wv = {w_a,w_b,w_c}  (Wl1/Wr1 [64,128] row-major)
        int i = w + 8 * j;
        float l1a = Wl1[i * 128 + l], l1b = Wl1[i * 128 + 64 + l];
        float r1a = Wr1[i * 128 + l], r1b = Wr1[i * 128 + 64 + l];
        float La = vl2[l], Lb = vl2[64 + l], Ra = vr2[l], Rb = vr2[64 + l];
        float pc = l1a * La + l1b * Lb;
        float pb = l1a * Ra + l1b * Rb + r1a * La + r1b * Lb;
        float pa = r1a * Ra + r1b * Rb;
        for (int m = 32; m; m >>= 1) {
            pa += __shfl_xor(pa, m); pb += __shfl_xor(pb, m); pc += __shfl_xor(pc, m);
        }
        if (l == 0) { wv[i] = pa; wv[64 + i] = pb; wv[128 + i] = pc; }
    }
    if (blockIdx.x == 0 && w == 7) {   // c0, c1 (block 0 publishes)
        float p0 = b1[l] * vr2[l] + b1[64 + l] * vr2[64 + l]
                 + b2[l] * uu[l] + b2[64 + l] * uu[64 + l];
        if (l < 32) p0 += bfc1[l] * w2[l];
        float p1 = b1[l] * vl2[l] + b1[64 + l] * vl2[64 + l];
        for (int m = 32; m; m >>= 1) { p0 += __shfl_xor(p0, m); p1 += __shfl_xor(p1, m); }
        if (l == 0) { c01[0] = p0 + bfc2[0]; c01[1] = p1; }
    }
    __syncthreads();   // wv/c01 ready

    // ---------------- wave-specialized: scatter (w<4) || dots (w>=4) ----------------
    bool is_scat = (w < 4);
    int e0 = blockIdx.x * CHUNK;
    int cnt = E - e0; if (cnt > CHUNK) cnt = CHUNK;
    int sd[EPTS], ss[EPTS];

    // dots setup (waves 4-7): 4 nodes/wave, float4, 16 lanes/node, 4 chunks
    int fp = l & 15, sub = l >> 4;
    float4 wa4, wb4, wc4;
    int dbase = 0, dstride = 1, KT = 0, KPP = 0;
    const float4* x4 = (const float4*)x;
    int Q = (N + 3) >> 2;
    if (!is_scat) {
        wa4 = ((const float4*)wv)[fp];
        wb4 = ((const float4*)wv)[16 + fp];
        wc4 = ((const float4*)wv)[32 + fp];
        dbase = blockIdx.x * 4 + (w - 4);
        dstride = gridDim.x * 4;
        KT = (Q - dbase + dstride - 1) / dstride;   // iterations for this wave
        if (KT < 0) KT = 0;
        KPP = (KT + 3) >> 2;                        // iterations per phase
    }
#define DOTS_PHASE(ph)                                                          \
    if (!is_scat) {                                                             \
        for (int k = (ph) * KPP; k < ((ph) + 1) * KPP && k < KT; ++k) {         \
            int node = (dbase + k * dstride) * 4 + sub;                         \
            float a = 0.f, b = 0.f, c = 0.f;                                    \
            if (node < N) {                                                     \
                float4 v = x4[(size_t)node * 16 + fp];                          \
                a = v.x * wa4.x + v.y * wa4.y + v.z * wa4.z + v.w * wa4.w;      \
                b = v.x * wb4.x + v.y * wb4.y + v.z * wb4.z + v.w * wb4.w;      \
                c = v.x * wc4.x + v.y * wc4.y + v.z * wc4.z + v.w * wc4.w;      \
            }                                                                   \
            for (int m = 8; m; m >>= 1) {                                       \
                a += __shfl_xor(a, m); b += __shfl_xor(b, m); c += __shfl_xor(c, m); \
            }                                                                   \
            if (fp == 0 && node < N) { ga[node] = a; gbc[node] = make_float2(b, c); } \
        }                                                                       \
    }

    // phase 0: zero hist | dots chunk 0
    if (is_scat) hist[t] = 0;
    DOTS_PHASE(0)
    __syncthreads();
    // phase 1: load edges into regs + LDS hist | dots chunk 1
    if (is_scat) {
        for (int k = 0; k < EPTS; ++k) {
            int i = t + k * 256;
            if (i < cnt) {
                sd[k] = dst[e0 + i];
                ss[k] = src[e0 + i];
                atomicAdd(&hist[sd[k] >> S_SHIFT], 1);
            }
        }
    }
    DOTS_PHASE(1)
    __syncthreads();
    // phase 2: reserve global bases | dots chunk 2
    if (is_scat) {
        lcur[t] = 0;
        if (t < B && hist[t] > 0) lbase[t] = atomicAdd(&cursor[t], hist[t]);
    }
    DOTS_PHASE(2)
    __syncthreads();
    // phase 3: placement | dots chunk 3
    if (is_scat) {
        for (int k = 0; k < EPTS; ++k) {
            int i = t + k * 256;
            if (i < cnt) {
                int bb = sd[k] >> S_SHIFT;
                int off = atomicAdd(&lcur[bb], 1);
                bucket[(size_t)bb * CAP + (unsigned)(lbase[bb] + off)] =
                    ((unsigned)ss[k] << S_SHIFT) | (unsigned)(sd[k] & (S_NODES - 1));
            }
        }
    }
    DOTS_PHASE(3)
#undef DOTS_PHASE
}

// One block per bucket, 1024 threads, 4-way replicated LDS accumulators (24 KB).
__global__ __launch_bounds__(1024) void aggA_kernel(
    const unsigned* __restrict__ bucket, const int* __restrict__ cursor,
    const float2* __restrict__ gbc, const float* __restrict__ ga,
    const float* __restrict__ c01,
    float* __restrict__ q, float* __restrict__ t1, float* __restrict__ inv, int N)
{
    __shared__ float aB[NREP][S_NODES], aC[NREP][S_NODES];
    __shared__ int cnt[NREP][S_NODES];
    int t = threadIdx.x, b = blockIdx.x;
    int r = (t >> 6) & (NREP - 1);
    float* aBf = (float*)aB; float* aCf = (float*)aC; int* cnf = (int*)cnt;
    for (int i = t; i < NREP * S_NODES; i += 1024) { aBf[i] = 0.f; aCf[i] = 0.f; cnf[i] = 0; }
    __syncthreads();
    int n = cursor[b];
    const unsigned* bp = bucket + (size_t)b * CAP;
    for (int i = t; i < n; i += 1024) {
        unsigned uu = bp[i];
        float2 g = gbc[uu >> S_SHIFT];   // 8B gather, 800KB L2-resident table
        int dl = uu & (S_NODES - 1);
        atomicAdd(&aB[r][dl], g.x);
        atomicAdd(&aC[r][dl], g.y);
        atomicAdd(&cnt[r][dl], 1);
    }
    __syncthreads();
    if (t < S_NODES) {
        int node = (b << S_SHIFT) + t;
        if (node < N) {
            float sb = aB[0][t] + aB[1][t] + aB[2][t] + aB[3][t];
            float sc = aC[0][t] + aC[1][t] + aC[2][t] + aC[3][t];
            int d = cnt[0][t] + cnt[1][t] + cnt[2][t] + cnt[3][t];
            float iv = 1.0f / ((d > 0) ? (float)d : 1.0f);
            inv[node] = iv;
            q[node]   = iv * sc;
            t1[node]  = ga[node] + iv * sb + c01[0] + (d > 0 ? c01[1] : 0.f);
        }
    }
}

__global__ __launch_bounds__(1024) void aggB_kernel(
    const unsigned* __restrict__ bucket, const int* __restrict__ cursor,
    const float* __restrict__ q, const float* __restrict__ t1,
    const float* __restrict__ inv, float* __restrict__ out, int N)
{
    __shared__ float a2[NREP][S_NODES];
    int t = threadIdx.x, b = blockIdx.x;
    int r = (t >> 6) & (NREP - 1);
    float* a2f = (float*)a2;
    for (int i = t; i < NREP * S_NODES; i += 1024) a2f[i] = 0.f;
    __syncthreads();
    int n = cursor[b];
    const unsigned* bp = bucket + (size_t)b * CAP;
    for (int i = t; i < n; i += 1024) {
        unsigned uu = bp[i];
        atomicAdd(&a2[r][uu & (S_NODES - 1)], q[uu >> S_SHIFT]);
    }
    __syncthreads();
    if (t < S_NODES) {
        int node = (b << S_SHIFT) + t;
        if (node < N)
            out[node] = t1[node] + inv[node] * (a2[0][t] + a2[1][t] + a2[2][t] + a2[3][t]);
    }
}

extern "C" void kernel_launch(void* const* d_in, const int* in_sizes, int n_in,
                              void* d_out, int out_size, void* d_ws, size_t ws_size,
                              hipStream_t stream) {
    const float* x    = (const float*)d_in[0];
    const int*   eidx = (const int*)d_in[1];   // [2, E]
    // d_in[2] = edge_weight: unused by the reference
    const float* Wl1  = (const float*)d_in[3];
    const float* Wr1  = (const float*)d_in[4];
    const float* b1   = (const float*)d_in[5];
    const float* Wl2  = (const float*)d_in[6];
    const float* Wr2  = (const float*)d_in[7];
    const float* b2   = (const float*)d_in[8];
    const float* Wfc1 = (const float*)d_in[9];
    const float* bfc1 = (const float*)d_in[10];
    const float* Wfc2 = (const float*)d_in[11];
    const float* bfc2 = (const float*)d_in[12];

    const int N = in_sizes[0] / 64;
    const int E = in_sizes[2];
    const int* src = eidx;
    const int* dst = eidx + E;
    const int B = (N + S_NODES - 1) / S_NODES;       // 196 buckets (<= 256)
    const int nprep = (E + CHUNK - 1) / CHUNK;       // 391 prep blocks

    // workspace: [cursor 1KB][c01 1KB][ga 4N][q 4N][t1 4N][inv 4N][gbc 8N][bucket B*CAP*4]
    char* ws = (char*)d_ws;
    int*      cursor = (int*)(ws);
    float*    c01    = (float*)(ws + 1024);
    float*    ga     = (float*)(ws + 2048);
    float*    q      = (float*)(ws + 2048 + (size_t)N * 4);
    float*    t1     = (float*)(ws + 2048 + (size_t)N * 8);
    float*    inv    = (float*)(ws + 2048 + (size_t)N * 12);
    float2*   gbc    = (float2*)(ws + 2048 + (size_t)N * 16);
    unsigned* bucket = (unsigned*)(ws + 2048 + (size_t)N * 24);

    hipMemsetAsync(cursor, 0, 1024, stream);

    prep_kernel<<<nprep, 512, 0, stream>>>(
        x, src, dst, E, N, B, cursor, bucket,
        Wl1, Wr1, b1, Wl2, Wr2, b2, Wfc1, bfc1, Wfc2, bfc2,
        ga, gbc, c01);

    aggA_kernel<<<B, 1024, 0, stream>>>(bucket, cursor, gbc, ga, c01, q, t1, inv, N);
    aggB_kernel<<<B, 1024, 0, stream>>>(bucket, cursor, q, t1, inv, (float*)d_out, N);
}

// Round 14
// 170.375 us; speedup vs baseline: 1.0599x; 1.0599x over previous
//
#include <hip/hip_runtime.h>

#define S_SHIFT 8
#define S_NODES 256          // nodes per bucket (dst_local = dst & 255)
#define NBKT    400          // LDS array size (>= B = 391)
#define CAP     5120         // bucket capacity (mean ~4092, +25% slack)
#define CHUNK   8192         // edges per scatter block
#define NREP    8            // LDS accumulator replicas: one per wave (512 thr)
#define FTH     512          // fused kernel block size
#define NDOTS   160          // dots-role blocks

// Fused: scatter role (blocks [0,nscat)) + fold/dots role (blocks [nscat,nscat+NDOTS)).
// Packed edge: (src << 8) | (dst & 255)   (src < 2^17 -> 25 bits)
__global__ __launch_bounds__(FTH) void fused_kernel(
    const float* __restrict__ x,
    const int* __restrict__ src, const int* __restrict__ dst,
    int E, int N, int B, int nscat,
    int* __restrict__ cursor, unsigned* __restrict__ bucket,
    const float* __restrict__ Wl1, const float* __restrict__ Wr1, const float* __restrict__ b1,
    const float* __restrict__ Wl2, const float* __restrict__ Wr2, const float* __restrict__ b2,
    const float* __restrict__ Wfc1, const float* __restrict__ bfc1,
    const float* __restrict__ Wfc2, const float* __restrict__ bfc2,
    float* __restrict__ ga, float2* __restrict__ gbc, float* __restrict__ c01)
{
    __shared__ int hist[NBKT], lbase[NBKT], lcur[NBKT];          // scatter role
    __shared__ float wv[192], uu[128], vl2[128], vr2[128], w2[32]; // dots role
    int t = threadIdx.x;
    int l = t & 63;          // lane
    int w = t >> 6;          // wave (0..7)

    if ((int)blockIdx.x < nscat) {
        // ---------------- scatter role ----------------
        int e0 = blockIdx.x * CHUNK;
        int cnt = E - e0; if (cnt > CHUNK) cnt = CHUNK;
        for (int i = t; i < B; i += FTH) hist[i] = 0;
        __syncthreads();
        for (int i = t; i < cnt; i += FTH)
            atomicAdd(&hist[dst[e0 + i] >> S_SHIFT], 1);
        __syncthreads();
        for (int i = t; i < B; i += FTH) {
            lcur[i] = 0;
            if (hist[i] > 0) lbase[i] = atomicAdd(&cursor[i], hist[i]);
        }
        __syncthreads();
        for (int i = t; i < cnt; i += FTH) {
            int d = dst[e0 + i], s = src[e0 + i];   // L2-hot re-read
            int bb = d >> S_SHIFT;
            int off = atomicAdd(&lcur[bb], 1);
            bucket[(size_t)bb * CAP + (unsigned)(lbase[bb] + off)] =
                ((unsigned)s << S_SHIFT) | (unsigned)(d & (S_NODES - 1));
        }
    } else {
        // ---------------- fold role (redundant per block, coalesced wave-per-row) ----------------
        if (t < 32) w2[t] = Wfc2[t];
        __syncthreads();
        for (int j = 0; j < 16; ++j) {   // uu = Wfc1 @ Wfc2  (Wfc1 [128,32] row-major)
            int i = w + 8 * j;
            float p = (l < 32) ? Wfc1[i * 32 + l] * w2[l] : 0.f;
            for (int m = 16; m; m >>= 1) p += __shfl_xor(p, m);
            if (l == 0) uu[i] = p;
        }
        __syncthreads();
        for (int j = 0; j < 16; ++j) {   // vl2 = Wl2 @ uu, vr2 = Wr2 @ uu ([128,128] row-major)
            int i = w + 8 * j;
            float ua = uu[l], ub = uu[64 + l];
            float pa = Wl2[i * 128 + l] * ua + Wl2[i * 128 + 64 + l] * ub;
            float pb = Wr2[i * 128 + l] * ua + Wr2[i * 128 + 64 + l] * ub;
            for (int m = 32; m; m >>= 1) { pa += __shfl_xor(pa, m); pb += __shfl_xor(pb, m); }
            if (l == 0) { vl2[i] = pa; vr2[i] = pb; }
        }
        __syncthreads();
        for (int j = 0; j < 8; ++j) {    // wv = {w_a,w_b,w_c}  (Wl1/Wr1 [64,128] row-major)
            int i = w + 8 * j;
            float l1a = Wl1[i * 128 + l], l1b = Wl1[i * 128 + 64 + l];
            float r1a = Wr1[i * 128 + l], r1b = Wr1[i * 128 + 64 + l];
            float La = vl2[l], Lb = vl2[64 + l], Ra = vr2[l], Rb = vr2[64 + l];
            float pc = l1a * La + l1b * Lb;
            float pb = l1a * Ra + l1b * Rb + r1a * La + r1b * Lb;
            float pa = r1a * Ra + r1b * Rb;
            for (int m = 32; m; m >>= 1) {
                pa += __shfl_xor(pa, m); pb += __shfl_xor(pb, m); pc += __shfl_xor(pc, m);
            }
            if (l == 0) { wv[i] = pa; wv[64 + i] = pb; wv[128 + i] = pc; }
        }
        if ((int)blockIdx.x == nscat && w == 7) {   // c0, c1 (one block publishes)
            float p0 = b1[l] * vr2[l] + b1[64 + l] * vr2[64 + l]
                     + b2[l] * uu[l] + b2[64 + l] * uu[64 + l];
            if (l < 32) p0 += bfc1[l] * w2[l];
            float p1 = b1[l] * vl2[l] + b1[64 + l] * vl2[64 + l];
            for (int m = 32; m; m >>= 1) { p0 += __shfl_xor(p0, m); p1 += __shfl_xor(p1, m); }
            if (l == 0) { c01[0] = p0 + bfc2[0]; c01[1] = p1; }
        }
        __syncthreads();

        // ---------------- dots: 4 nodes/wave, float4, 16 lanes per node ----------------
        int fp = l & 15, sub = l >> 4;
        float4 wa4 = ((const float4*)wv)[fp];
        float4 wb4 = ((const float4*)wv)[16 + fp];
        float4 wc4 = ((const float4*)wv)[32 + fp];
        const float4* x4 = (const float4*)x;
        int Q = (N + 3) >> 2;
        for (int qd = ((int)blockIdx.x - nscat) * 8 + w; qd < Q; qd += NDOTS * 8) {
            int node = qd * 4 + sub;
            float a = 0.f, b = 0.f, c = 0.f;
            if (node < N) {
                float4 v = x4[(size_t)node * 16 + fp];
                a = v.x * wa4.x + v.y * wa4.y + v.z * wa4.z + v.w * wa4.w;
                b = v.x * wb4.x + v.y * wb4.y + v.z * wb4.z + v.w * wb4.w;
                c = v.x * wc4.x + v.y * wc4.y + v.z * wc4.z + v.w * wc4.w;
            }
            for (int m = 8; m; m >>= 1) {
                a += __shfl_xor(a, m); b += __shfl_xor(b, m); c += __shfl_xor(c, m);
            }
            if (fp == 0 && node < N) { ga[node] = a; gbc[node] = make_float2(b, c); }
        }
    }
}

// One block per bucket, 512 threads, per-wave (8x) replicated LDS accumulators.
// uint4 bucket reads: 4 edges/thread/iter -> 4x MLP on the gbc gathers.
__global__ __launch_bounds__(512) void aggA_kernel(
    const unsigned* __restrict__ bucket, const int* __restrict__ cursor,
    const float2* __restrict__ gbc, const float* __restrict__ ga,
    const float* __restrict__ c01,
    float* __restrict__ q, float* __restrict__ t1, float* __restrict__ inv, int N)
{
    __shared__ float aB[NREP][S_NODES], aC[NREP][S_NODES];
    __shared__ int cnt[NREP][S_NODES];
    int t = threadIdx.x, b = blockIdx.x;
    int r = t >> 6;                       // private replica per wave
    float* aBf = (float*)aB; float* aCf = (float*)aC; int* cnf = (int*)cnt;
    for (int i = t; i < NREP * S_NODES; i += 512) { aBf[i] = 0.f; aCf[i] = 0.f; cnf[i] = 0; }
    __syncthreads();
    int n = cursor[b];
    const unsigned* bp = bucket + (size_t)b * CAP;
    int n4 = n & ~3;
    for (int i = 4 * t; i < n4; i += 4 * 512) {
        uint4 e4 = *(const uint4*)(bp + i);
        float2 g0 = gbc[e4.x >> S_SHIFT];
        float2 g1 = gbc[e4.y >> S_SHIFT];
        float2 g2 = gbc[e4.z >> S_SHIFT];
        float2 g3 = gbc[e4.w >> S_SHIFT];
        int d0 = e4.x & (S_NODES - 1), d1 = e4.y & (S_NODES - 1);
        int d2 = e4.z & (S_NODES - 1), d3 = e4.w & (S_NODES - 1);
        atomicAdd(&aB[r][d0], g0.x); atomicAdd(&aC[r][d0], g0.y); atomicAdd(&cnt[r][d0], 1);
        atomicAdd(&aB[r][d1], g1.x); atomicAdd(&aC[r][d1], g1.y); atomicAdd(&cnt[r][d1], 1);
        atomicAdd(&aB[r][d2], g2.x); atomicAdd(&aC[r][d2], g2.y); atomicAdd(&cnt[r][d2], 1);
        atomicAdd(&aB[r][d3], g3.x); atomicAdd(&aC[r][d3], g3.y); atomicAdd(&cnt[r][d3], 1);
    }
    if (n4 + t < n) {
        unsigned uu = bp[n4 + t];
        float2 g = gbc[uu >> S_SHIFT];
        int dl = uu & (S_NODES - 1);
        atomicAdd(&aB[r][dl], g.x); atomicAdd(&aC[r][dl], g.y); atomicAdd(&cnt[r][dl], 1);
    }
    __syncthreads();
    if (t < S_NODES) {
        int node = (b << S_SHIFT) + t;
        if (node < N) {
            float sb = 0.f, sc = 0.f; int d = 0;
            #pragma unroll
            for (int k = 0; k < NREP; ++k) { sb += aB[k][t]; sc += aC[k][t]; d += cnt[k][t]; }
            float iv = 1.0f / ((d > 0) ? (float)d : 1.0f);
            inv[node] = iv;
            q[node]   = iv * sc;
            t1[node]  = ga[node] + iv * sb + c01[0] + (d > 0 ? c01[1] : 0.f);
        }
    }
}

__global__ __launch_bounds__(512) void aggB_kernel(
    const unsigned* __restrict__ bucket, const int* __restrict__ cursor,
    const float* __restrict__ q, const float* __restrict__ t1,
    const float* __restrict__ inv, float* __restrict__ out, int N)
{
    __shared__ float a2[NREP][S_NODES];
    int t = threadIdx.x, b = blockIdx.x;
    int r = t >> 6;
    float* a2f = (float*)a2;
    for (int i = t; i < NREP * S_NODES; i += 512) a2f[i] = 0.f;
    __syncthreads();
    int n = cursor[b];
    const unsigned* bp = bucket + (size_t)b * CAP;
    int n4 = n & ~3;
    for (int i = 4 * t; i < n4; i += 4 * 512) {
        uint4 e4 = *(const uint4*)(bp + i);
        float q0 = q[e4.x >> S_SHIFT], q1 = q[e4.y >> S_SHIFT];
        float q2 = q[e4.z >> S_SHIFT], q3 = q[e4.w >> S_SHIFT];
        atomicAdd(&a2[r][e4.x & (S_NODES - 1)], q0);
        atomicAdd(&a2[r][e4.y & (S_NODES - 1)], q1);
        atomicAdd(&a2[r][e4.z & (S_NODES - 1)], q2);
        atomicAdd(&a2[r][e4.w & (S_NODES - 1)], q3);
    }
    if (n4 + t < n) {
        unsigned uu = bp[n4 + t];
        atomicAdd(&a2[r][uu & (S_NODES - 1)], q[uu >> S_SHIFT]);
    }
    __syncthreads();
    if (t < S_NODES) {
        int node = (b << S_SHIFT) + t;
        if (node < N) {
            float s2 = 0.f;
            #pragma unroll
            for (int k = 0; k < NREP; ++k) s2 += a2[k][t];
            out[node] = t1[node] + inv[node] * s2;
        }
    }
}

extern "C" void kernel_launch(void* const* d_in, const int* in_sizes, int n_in,
                              void* d_out, int out_size, void* d_ws, size_t ws_size,
                              hipStream_t stream) {
    const float* x    = (const float*)d_in[0];
    const int*   eidx = (const int*)d_in[1];   // [2, E]
    // d_in[2] = edge_weight: unused by the reference
    const float* Wl1  = (const float*)d_in[3];
    const float* Wr1  = (const float*)d_in[4];
    const float* b1   = (const float*)d_in[5];
    const float* Wl2  = (const float*)d_in[6];
    const float* Wr2  = (const float*)d_in[7];
    const float* b2   = (const float*)d_in[8];
    const float* Wfc1 = (const float*)d_in[9];
    const float* bfc1 = (const float*)d_in[10];
    const float* Wfc2 = (const float*)d_in[11];
    const float* bfc2 = (const float*)d_in[12];

    const int N = in_sizes[0] / 64;
    const int E = in_sizes[2];
    const int* src = eidx;
    const int* dst = eidx + E;
    const int B = (N + S_NODES - 1) / S_NODES;       // 391 buckets (<= NBKT)
    const int nscat = (E + CHUNK - 1) / CHUNK;       // 196 scatter blocks

    // workspace: [cursor 2KB][c01 2KB][ga 4N][q 4N][t1 4N][inv 4N][gbc 8N][bucket B*CAP*4]
    char* ws = (char*)d_ws;
    int*      cursor = (int*)(ws);
    float*    c01    = (float*)(ws + 2048);
    float*    ga     = (float*)(ws + 4096);
    float*    q      = (float*)(ws + 4096 + (size_t)N * 4);
    float*    t1     = (float*)(ws + 4096 + (size_t)N * 8);
    float*    inv    = (float*)(ws + 4096 + (size_t)N * 12);
    float2*   gbc    = (float2*)(ws + 4096 + (size_t)N * 16);
    unsigned* bucket = (unsigned*)(ws + 4096 + (size_t)N * 24);

    hipMemsetAsync(cursor, 0, 2048, stream);

    fused_kernel<<<nscat + NDOTS, FTH, 0, stream>>>(
        x, src, dst, E, N, B, nscat, cursor, bucket,
        Wl1, Wr1, b1, Wl2, Wr2, b2, Wfc1, bfc1, Wfc2, bfc2,
        ga, gbc, c01);

    aggA_kernel<<<B, 512, 0, stream>>>(bucket, cursor, gbc, ga, c01, q, t1, inv, N);
    aggB_kernel<<<B, 512, 0, stream>>>(bucket, cursor, q, t1, inv, (float*)d_out, N);
}